// Round 5
// baseline (1825145.898 us; speedup 1.0000x reference)
//
#include <hip/hip_runtime.h>

#define T_STEPS 512
#define BATCH   64
#define DIMS    256
#define NBLK    16   // blocks per squad (= per direction replica)
#define NDIR    2
#define NLAUNCH 256  // launched blocks; first 16 claimants per XCD form a squad

typedef short bf16x8 __attribute__((ext_vector_type(8)));
typedef float f32x4  __attribute__((ext_vector_type(4)));
typedef unsigned int u32x4 __attribute__((ext_vector_type(4)));

// s_getreg_b32 imm encoding: id | (offset<<6) | ((width-1)<<11); HW_REG_XCC_ID = 20
#define HWREG_XCC_ID_FULL (20 | (0 << 6) | (31 << 11))

__device__ __forceinline__ unsigned short f2bf(float f) {
  union { float f; unsigned int u; } v; v.f = f;
  unsigned int b = v.u;
  return (unsigned short)((b + 0x7FFFu + ((b >> 16) & 1u)) >> 16);
}

__device__ __forceinline__ float sigm(float x) {
  return __builtin_amdgcn_rcpf(1.0f + __builtin_amdgcn_exp2f(-1.44269504f * x));
}
__device__ __forceinline__ float tanh_(float x) {
  return 1.0f - 2.0f * __builtin_amdgcn_rcpf(1.0f + __builtin_amdgcn_exp2f(2.88539008f * x));
}

__device__ __forceinline__ f32x4 bcast4(float s) {
  f32x4 v; v[0] = s; v[1] = s; v[2] = s; v[3] = s; return v;
}

// ---- prep: x (f32) -> bf16, [64][512][256] layout unchanged ----
__global__ void prep_x(const float* __restrict__ x, unsigned short* __restrict__ xbf) {
  size_t i = ((size_t)blockIdx.x * 256 + threadIdx.x) * 4;
  const float4 v = *reinterpret_cast<const float4*>(x + i);
  uint2 o;
  o.x = (unsigned)f2bf(v.x) | ((unsigned)f2bf(v.y) << 16);
  o.y = (unsigned)f2bf(v.z) | ((unsigned)f2bf(v.w) << 16);
  *reinterpret_cast<uint2*>(xbf + i) = o;
}

// ---- prep: W [512][1024] f32 -> WT [2][1024 cols][512 k] bf16 (transposed) ----
__global__ void prep_w(const float* __restrict__ Wf, const float* __restrict__ Wb,
                       unsigned short* __restrict__ WT) {
  int d = blockIdx.x >> 10, col = blockIdx.x & 1023;
  const float* W = d ? Wb : Wf;
  int k = threadIdx.x;
  WT[((size_t)(d * 1024 + col)) * 512 + k] = f2bf(W[(size_t)k * 1024 + col]);
}

// ---- persistent recurrence, XCD-local squads ----
// 256 blocks launched (all co-resident: 2 blocks/CU). Each block reads its
// physical XCD id (HW_REG_XCC_ID) and claims a roster slot; the first 16
// claimants on an XCD form a squad. Squad leaders claim directions globally:
// claim 0 -> dir0, claim 1 -> dir1, others exit. >=2 complete squads always
// form (pigeonhole: <=1 squad would need total <= 64 + 7*15 = 169 < 256).
// All h exchange inside a squad goes through the XCD's shared L2 with
// sc0-only loads/stores (L1 bypass; same-XCD L2 is the coherence point).
// Flag-in-data: h words are uint32 (tag<<16 | bf16), self-validating.
__global__ __launch_bounds__(256, 1) void lstm_rec(
    const unsigned short* __restrict__ xbf,   // [64][512][256] bf16
    const unsigned short* __restrict__ WT,    // [2][1024][512] bf16
    const float* __restrict__ bias_f, const float* __restrict__ bias_b,
    const float* __restrict__ ci_f, const float* __restrict__ hi_f,
    const float* __restrict__ ci_b, const float* __restrict__ hi_b,
    const int* __restrict__ length,
    unsigned int* hbuf,     // [2 dir][2 slot][64][256] u32 (tag<<16 | bf16 h)
    float* hfinal,          // [2 dir][64][256] f32
    int* ctrl)              // [0..7] roster, [8] dirclaim, [16..23] xcd->dir+1
{
  __shared__ int s_dir, s_g;
  if (threadIdx.x == 0) {
    const int xcc = __builtin_amdgcn_s_getreg(HWREG_XCC_ID_FULL) & 7;
    const int idx = __hip_atomic_fetch_add(&ctrl[xcc], 1,
                                           __ATOMIC_RELAXED, __HIP_MEMORY_SCOPE_AGENT);
    int dir = 2, g = -1;
    if (idx < NBLK) {
      g = idx;
      if (idx == 0) {
        const int r = __hip_atomic_fetch_add(&ctrl[8], 1,
                                             __ATOMIC_RELAXED, __HIP_MEMORY_SCOPE_AGENT);
        dir = (r < NDIR) ? r : 2;
        __hip_atomic_store(&ctrl[16 + xcc], dir + 1,
                           __ATOMIC_RELEASE, __HIP_MEMORY_SCOPE_AGENT);
      } else {
        int v, spins = 0;
        do {
          v = __hip_atomic_load(&ctrl[16 + xcc],
                                __ATOMIC_ACQUIRE, __HIP_MEMORY_SCOPE_AGENT);
          if (++spins > (1 << 22)) v = 3;   // escape -> exit, bench fails visibly
        } while (v == 0);
        dir = v - 1;
      }
    }
    s_dir = dir; s_g = g;
  }
  __syncthreads();
  const int dir = s_dir, g = s_g;
  if (g < 0 || dir >= NDIR) return;

  const int lane = threadIdx.x & 63;
  const int wv = threadIdx.x >> 6;
  const int lhi = lane >> 4, llo = lane & 15;

  const float* bias = dir ? bias_b : bias_f;
  const float* cini = dir ? ci_b : ci_f;
  const float* hini = dir ? hi_b : hi_f;
  unsigned int* hb = hbuf + (size_t)dir * (2 * BATCH * DIMS);

  const int dim = g * 16 + llo;   // owned h-dim (MFMA N-col within tile = llo)

  // B-fragments of W: wf[gate][kstep], ks 0..7 = x rows, 8..15 = h rows.
  // Pinned via volatile asm so the loads cannot be rematerialized in-loop.
  bf16x8 wf[4][16];
  #pragma unroll
  for (int gate = 0; gate < 4; ++gate) {
    #pragma unroll
    for (int ks = 0; ks < 16; ++ks) {
      const unsigned short* p =
          WT + ((size_t)(dir * 1024 + gate * 256 + dim)) * 512 + ks * 32 + lhi * 8;
      wf[gate][ks] = *reinterpret_cast<const bf16x8*>(p);
      asm volatile("" : "+v"(wf[gate][ks]));
    }
  }
  float bs[4];
  #pragma unroll
  for (int gate = 0; gate < 4; ++gate) bs[gate] = bias[gate * 256 + dim];

  // C/D layout: row(batch) = wv*16 + lhi*4 + j, col(dim) = llo
  const int b0 = wv * 16 + lhi * 4;
  float c[4], h[4];
  int Ld[4];
  #pragma unroll
  for (int j = 0; j < 4; ++j) {
    c[j] = cini[dim]; h[j] = hini[dim]; Ld[j] = length[b0 + j];
  }

  // A layout: row(batch) = wv*16 + llo, k = kstep*32 + lhi*8 + e
  const int bx = wv * 16 + llo;
  const int Lx = length[bx];

  // publish h^0 (tag=1) into slot 0 — sc0: write-through to this XCD's L2
  #pragma unroll
  for (int j = 0; j < 4; ++j) {
    unsigned int val = (1u << 16) | (unsigned int)f2bf(h[j]);
    const unsigned int* ap = hb + (b0 + j) * DIMS + dim;
    asm volatile("global_store_dword %0, %1, off sc0"
                 :: "v"(ap), "v"(val) : "memory");
  }

  // preload x A-fragments for t=0 (normal cached loads)
  bf16x8 xa[8];
  {
    const int tx0 = (dir == 0) ? 0 : (Lx - 1);
    const unsigned short* xp = xbf + ((size_t)bx * T_STEPS + tx0) * DIMS + lhi * 8;
    #pragma unroll
    for (int ks = 0; ks < 8; ++ks) xa[ks] = *reinterpret_cast<const bf16x8*>(xp + ks * 32);
  }

  #pragma unroll 1
  for (int t = 0; t < T_STEPS; ++t) {
    f32x4 acc[4];
    #pragma unroll
    for (int gate = 0; gate < 4; ++gate) acc[gate] = bcast4(bs[gate]);

    // x-part (independent of h^t): runs while producers finish step t-1
    #pragma unroll
    for (int ks = 0; ks < 8; ++ks) {
      #pragma unroll
      for (int gate = 0; gate < 4; ++gate)
        acc[gate] = __builtin_amdgcn_mfma_f32_16x16x32_bf16(xa[ks], wf[gate][ks], acc[gate], 0, 0, 0);
    }

    // poll own k-slice of h^t in L2 until all 64 words carry tag t+1
    const unsigned int* hr = hb + (size_t)(t & 1) * (BATCH * DIMS) + bx * DIMS + lhi * 8;
    u32x4 w[16];
    {
      const unsigned int tagsh = (unsigned int)(t + 1) << 16;
      unsigned int iters = 0;
      bool ready;
      do {
        #pragma unroll
        for (int ks = 0; ks < 8; ++ks) {
          const unsigned int* p = hr + ks * 32;
          asm volatile("global_load_dwordx4 %0, %1, off sc0"
                       : "=v"(w[2 * ks]) : "v"(p) : "memory");
          asm volatile("global_load_dwordx4 %0, %1, off sc0"
                       : "=v"(w[2 * ks + 1]) : "v"(p + 4) : "memory");
        }
        asm volatile("s_waitcnt vmcnt(0)" ::: "memory");
        unsigned int bad = 0;
        #pragma unroll
        for (int i = 0; i < 16; ++i)
          #pragma unroll
          for (int q = 0; q < 4; ++q)
            bad |= (w[i][q] ^ tagsh);
        ready = ((bad >> 16) == 0);
        if (++iters > (1u << 20)) break;   // placement-failure escape (visible fail)
      } while (!__all(ready));
    }
    __builtin_amdgcn_sched_barrier(0);

    // repack low halves -> bf16x8 A-fragments
    bf16x8 ha[8];
    #pragma unroll
    for (int ks = 0; ks < 8; ++ks) {
      union { bf16x8 v; unsigned int dd[4]; } u;
      u.dd[0] = (w[2 * ks][0]     & 0xFFFFu) | (w[2 * ks][1]     << 16);
      u.dd[1] = (w[2 * ks][2]     & 0xFFFFu) | (w[2 * ks][3]     << 16);
      u.dd[2] = (w[2 * ks + 1][0] & 0xFFFFu) | (w[2 * ks + 1][1] << 16);
      u.dd[3] = (w[2 * ks + 1][2] & 0xFFFFu) | (w[2 * ks + 1][3] << 16);
      ha[ks] = u.v;
    }

    // prefetch x A-fragments for t+1 (cached; drained by next poll's vmcnt)
    if (t + 1 < T_STEPS) {
      const int tn = t + 1;
      const int tx = (dir == 0) ? tn : ((tn < Lx) ? (Lx - 1 - tn) : tn);
      const unsigned short* xp = xbf + ((size_t)bx * T_STEPS + tx) * DIMS + lhi * 8;
      #pragma unroll
      for (int ks = 0; ks < 8; ++ks) xa[ks] = *reinterpret_cast<const bf16x8*>(xp + ks * 32);
    }

    #pragma unroll
    for (int ks = 0; ks < 8; ++ks) {
      #pragma unroll
      for (int gate = 0; gate < 4; ++gate)
        acc[gate] = __builtin_amdgcn_mfma_f32_16x16x32_bf16(ha[ks], wf[gate][ks + 8], acc[gate], 0, 0, 0);
    }

    // gate order (cudnn-compatible): i, g, f, o — then publish h^{t+1} (tag t+2)
    unsigned int* hw = hb + (size_t)((t + 1) & 1) * (BATCH * DIMS);
    const unsigned int ptag = (unsigned int)(t + 2) << 16;
    #pragma unroll
    for (int j = 0; j < 4; ++j) {
      const float gi = acc[0][j], gg = acc[1][j], gf = acc[2][j], go = acc[3][j];
      const float cn = sigm(gf) * c[j] + sigm(gi) * tanh_(gg);
      const float hn = tanh_(cn) * sigm(go);
      if (t < Ld[j]) { c[j] = cn; h[j] = hn; }   // freeze at t >= length
      unsigned int val = ptag | (unsigned int)f2bf(h[j]);
      const unsigned int* ap = hw + (b0 + j) * DIMS + dim;
      asm volatile("global_store_dword %0, %1, off sc0"
                   :: "v"(ap), "v"(val) : "memory");
    }
  }

  // final frozen h in f32
  #pragma unroll
  for (int j = 0; j < 4; ++j)
    hfinal[((size_t)dir * BATCH + b0 + j) * DIMS + dim] = h[j];
}

// ---- out[64,256] = concat(h_f, h_b) @ W_fc[512,256], f32 ----
__global__ void final_gemm(const float* __restrict__ hfinal, const float* __restrict__ Wfc,
                           float* __restrict__ out) {
  __shared__ float hrow[512];
  const int b = blockIdx.x, col = threadIdx.x;
  hrow[col]       = hfinal[(size_t)b * DIMS + col];
  hrow[256 + col] = hfinal[(size_t)(BATCH + b) * DIMS + col];
  __syncthreads();
  float acc = 0.f;
  #pragma unroll 8
  for (int k = 0; k < 512; ++k) acc = fmaf(hrow[k], Wfc[(size_t)k * DIMS + col], acc);
  out[(size_t)b * DIMS + col] = acc;
}

extern "C" void kernel_launch(void* const* d_in, const int* in_sizes, int n_in,
                              void* d_out, int out_size, void* d_ws, size_t ws_size,
                              hipStream_t stream) {
  const float* x        = (const float*)d_in[0];
  const int*   length   = (const int*)d_in[1];
  const float* W_f      = (const float*)d_in[2];
  const float* b_f      = (const float*)d_in[3];
  const float* W_b      = (const float*)d_in[4];
  const float* b_b      = (const float*)d_in[5];
  const float* c_init_f = (const float*)d_in[6];
  const float* h_init_f = (const float*)d_in[7];
  const float* c_init_b = (const float*)d_in[8];
  const float* h_init_b = (const float*)d_in[9];
  const float* W_fc     = (const float*)d_in[10];
  float* out = (float*)d_out;

  char* ws = (char*)d_ws;
  unsigned short* xbf = (unsigned short*)(ws);                        // 16,777,216 B
  unsigned short* WT  = (unsigned short*)(ws + 16777216);             //  2,097,152 B
  unsigned int*   hbf = (unsigned int*)(ws + 16777216 + 2097152);     //    524,288 B
  int*   ctrl         = (int*)(ws + 16777216 + 2097152 + 524288);     //      4,096 B
  float* hfinal       = (float*)(ws + 16777216 + 2097152 + 524288 + 4096);  // 131,072 B

  // zero tags + control each call (hbuf and ctrl are contiguous)
  hipMemsetAsync(hbf, 0, 524288 + 4096, stream);
  prep_x<<<8192, 256, 0, stream>>>(x, xbf);
  prep_w<<<2048, 512, 0, stream>>>(W_f, W_b, WT);
  lstm_rec<<<NLAUNCH, 256, 0, stream>>>(xbf, WT, b_f, b_b,
                                        c_init_f, h_init_f, c_init_b, h_init_b,
                                        length, hbf, hfinal, ctrl);
  final_gemm<<<BATCH, 256, 0, stream>>>(hfinal, W_fc, out);
}

// Round 6
// 2662.734 us; speedup vs baseline: 685.4405x; 685.4405x over previous
//
#include <hip/hip_runtime.h>

#define T_STEPS 512
#define BATCH   64
#define DIMS    256
#define NBLK    16   // blocks per direction
#define NDIR    2

typedef short bf16x8 __attribute__((ext_vector_type(8)));
typedef float f32x4  __attribute__((ext_vector_type(4)));
typedef unsigned int u32x4 __attribute__((ext_vector_type(4)));

__device__ __forceinline__ unsigned short f2bf(float f) {
  union { float f; unsigned int u; } v; v.f = f;
  unsigned int b = v.u;
  return (unsigned short)((b + 0x7FFFu + ((b >> 16) & 1u)) >> 16);
}

__device__ __forceinline__ float sigm(float x) {
  return __builtin_amdgcn_rcpf(1.0f + __builtin_amdgcn_exp2f(-1.44269504f * x));
}
__device__ __forceinline__ float tanh_(float x) {
  return 1.0f - 2.0f * __builtin_amdgcn_rcpf(1.0f + __builtin_amdgcn_exp2f(2.88539008f * x));
}

__device__ __forceinline__ f32x4 bcast4(float s) {
  f32x4 v; v[0] = s; v[1] = s; v[2] = s; v[3] = s; return v;
}

// ---- prep: x (f32) -> bf16, [64][512][256] layout unchanged ----
__global__ void prep_x(const float* __restrict__ x, unsigned short* __restrict__ xbf) {
  size_t i = ((size_t)blockIdx.x * 256 + threadIdx.x) * 4;
  const float4 v = *reinterpret_cast<const float4*>(x + i);
  uint2 o;
  o.x = (unsigned)f2bf(v.x) | ((unsigned)f2bf(v.y) << 16);
  o.y = (unsigned)f2bf(v.z) | ((unsigned)f2bf(v.w) << 16);
  *reinterpret_cast<uint2*>(xbf + i) = o;
}

// ---- prep: W [512][1024] f32 -> WT [2][1024 cols][512 k] bf16 (transposed) ----
__global__ void prep_w(const float* __restrict__ Wf, const float* __restrict__ Wb,
                       unsigned short* __restrict__ WT) {
  int d = blockIdx.x >> 10, col = blockIdx.x & 1023;
  const float* W = d ? Wb : Wf;
  int k = threadIdx.x;
  WT[((size_t)(d * 1024 + col)) * 512 + k] = f2bf(W[(size_t)k * 1024 + col]);
}

// ---- persistent recurrence: 32 blocks (16/dir), W register-resident ----
// Cross-block exchange is flag-in-data: h words are uint32 (tag<<16 | bf16),
// moved with sc1-only (AGENT-scope) loads/stores -> coherent at the MALL,
// L1-bypassed, NOT system-scope (sc0 sc1 would force HBM). Consumers issue
// their h-load batch speculatively before the x-MFMA phase; first tag check
// uses vmcnt(4) (the 4 publish stores may still be in flight; a register not
// yet overwritten holds a stale tag <= t-1 != t+1, so mid-flight reads can
// only cause a harmless retry, never a false accept).
__global__ __launch_bounds__(256, 1) void lstm_rec(
    const unsigned short* __restrict__ xbf,   // [64][512][256] bf16
    const unsigned short* __restrict__ WT,    // [2][1024][512] bf16
    const float* __restrict__ bias_f, const float* __restrict__ bias_b,
    const float* __restrict__ ci_f, const float* __restrict__ hi_f,
    const float* __restrict__ ci_b, const float* __restrict__ hi_b,
    const int* __restrict__ length,
    unsigned int* hbuf,     // [2 dir][2 slot][64][256] u32 (tag<<16 | bf16 h)
    float* hfinal)          // [2 dir][64][256] f32
{
  const int blk = blockIdx.x;
  const int d = blk >> 4, g = blk & 15;
  const int lane = threadIdx.x & 63;
  const int wv = threadIdx.x >> 6;
  const int lhi = lane >> 4, llo = lane & 15;

  const float* bias = d ? bias_b : bias_f;
  const float* cini = d ? ci_b : ci_f;
  const float* hini = d ? hi_b : hi_f;
  unsigned int* hb = hbuf + (size_t)d * (2 * BATCH * DIMS);

  const int dim = g * 16 + llo;   // owned h-dim (MFMA N-col within tile = llo)

  // B-fragments of W: wf[gate][kstep], ks 0..7 = x rows, 8..15 = h rows.
  // Pinned via volatile asm so the loads cannot be rematerialized in-loop.
  bf16x8 wf[4][16];
  #pragma unroll
  for (int gate = 0; gate < 4; ++gate) {
    #pragma unroll
    for (int ks = 0; ks < 16; ++ks) {
      const unsigned short* p =
          WT + ((size_t)(d * 1024 + gate * 256 + dim)) * 512 + ks * 32 + lhi * 8;
      wf[gate][ks] = *reinterpret_cast<const bf16x8*>(p);
      asm volatile("" : "+v"(wf[gate][ks]));
    }
  }
  float bs[4];
  #pragma unroll
  for (int gate = 0; gate < 4; ++gate) bs[gate] = bias[gate * 256 + dim];

  // C/D layout: row(batch) = wv*16 + lhi*4 + j, col(dim) = llo
  const int b0 = wv * 16 + lhi * 4;
  float c[4], h[4];
  int Ld[4];
  #pragma unroll
  for (int j = 0; j < 4; ++j) {
    c[j] = cini[dim]; h[j] = hini[dim]; Ld[j] = length[b0 + j];
  }

  // A layout: row(batch) = wv*16 + llo, k = kstep*32 + lhi*8 + e
  const int bx = wv * 16 + llo;
  const int Lx = length[bx];

  // publish h^0 (tag=1) into slot 0 — agent scope (sc1)
  #pragma unroll
  for (int j = 0; j < 4; ++j) {
    unsigned int val = (1u << 16) | (unsigned int)f2bf(h[j]);
    const unsigned int* ap = hb + (b0 + j) * DIMS + dim;
    asm volatile("global_store_dword %0, %1, off sc1"
                 :: "v"(ap), "v"(val) : "memory");
  }

  // preload x A-fragments for t=0 (normal cached loads)
  bf16x8 xa[8];
  {
    const int tx0 = (d == 0) ? 0 : (Lx - 1);
    const unsigned short* xp = xbf + ((size_t)bx * T_STEPS + tx0) * DIMS + lhi * 8;
    #pragma unroll
    for (int ks = 0; ks < 8; ++ks) xa[ks] = *reinterpret_cast<const bf16x8*>(xp + ks * 32);
  }

  #pragma unroll 1
  for (int t = 0; t < T_STEPS; ++t) {
    // speculative poll issue: h^t loads in flight while x-MFMA runs
    const unsigned int* hr = hb + (size_t)(t & 1) * (BATCH * DIMS) + bx * DIMS + lhi * 8;
    u32x4 w[16];
    #pragma unroll
    for (int ks = 0; ks < 8; ++ks) {
      const unsigned int* p = hr + ks * 32;
      asm volatile("global_load_dwordx4 %0, %1, off sc1"
                   : "=v"(w[2 * ks]) : "v"(p) : "memory");
      asm volatile("global_load_dwordx4 %0, %1, off sc1"
                   : "=v"(w[2 * ks + 1]) : "v"(p + 4) : "memory");
    }

    f32x4 acc[4];
    #pragma unroll
    for (int gate = 0; gate < 4; ++gate) acc[gate] = bcast4(bs[gate]);

    // x-part (independent of h^t): covers the poll loads' flight time
    #pragma unroll
    for (int ks = 0; ks < 8; ++ks) {
      #pragma unroll
      for (int gate = 0; gate < 4; ++gate)
        acc[gate] = __builtin_amdgcn_mfma_f32_16x16x32_bf16(xa[ks], wf[gate][ks], acc[gate], 0, 0, 0);
    }

    // tag check: all 64 words must carry tag t+1
    const unsigned int tagsh = (unsigned int)(t + 1) << 16;
    if (t == 0) asm volatile("s_waitcnt vmcnt(0)" ::: "memory");
    else        asm volatile("s_waitcnt vmcnt(4)" ::: "memory");
    bool ready;
    {
      unsigned int bad = 0;
      #pragma unroll
      for (int i = 0; i < 16; ++i)
        #pragma unroll
        for (int q = 0; q < 4; ++q)
          bad |= (w[i][q] ^ tagsh);
      ready = ((bad >> 16) == 0);
    }
    while (!__all(ready)) {
      #pragma unroll
      for (int ks = 0; ks < 8; ++ks) {
        const unsigned int* p = hr + ks * 32;
        asm volatile("global_load_dwordx4 %0, %1, off sc1"
                     : "=v"(w[2 * ks]) : "v"(p) : "memory");
        asm volatile("global_load_dwordx4 %0, %1, off sc1"
                     : "=v"(w[2 * ks + 1]) : "v"(p + 4) : "memory");
      }
      asm volatile("s_waitcnt vmcnt(0)" ::: "memory");
      unsigned int bad = 0;
      #pragma unroll
      for (int i = 0; i < 16; ++i)
        #pragma unroll
        for (int q = 0; q < 4; ++q)
          bad |= (w[i][q] ^ tagsh);
      ready = ((bad >> 16) == 0);
    }
    __builtin_amdgcn_sched_barrier(0);

    // prefetch x A-fragments for t+1 (cached; issued early, used next iter)
    if (t + 1 < T_STEPS) {
      const int tn = t + 1;
      const int tx = (d == 0) ? tn : ((tn < Lx) ? (Lx - 1 - tn) : tn);
      const unsigned short* xp = xbf + ((size_t)bx * T_STEPS + tx) * DIMS + lhi * 8;
      #pragma unroll
      for (int ks = 0; ks < 8; ++ks) xa[ks] = *reinterpret_cast<const bf16x8*>(xp + ks * 32);
    }

    // repack low halves -> bf16x8 A-fragments
    bf16x8 ha[8];
    #pragma unroll
    for (int ks = 0; ks < 8; ++ks) {
      union { bf16x8 v; unsigned int dd[4]; } u;
      u.dd[0] = (w[2 * ks][0]     & 0xFFFFu) | (w[2 * ks][1]     << 16);
      u.dd[1] = (w[2 * ks][2]     & 0xFFFFu) | (w[2 * ks][3]     << 16);
      u.dd[2] = (w[2 * ks + 1][0] & 0xFFFFu) | (w[2 * ks + 1][1] << 16);
      u.dd[3] = (w[2 * ks + 1][2] & 0xFFFFu) | (w[2 * ks + 1][3] << 16);
      ha[ks] = u.v;
    }

    #pragma unroll
    for (int ks = 0; ks < 8; ++ks) {
      #pragma unroll
      for (int gate = 0; gate < 4; ++gate)
        acc[gate] = __builtin_amdgcn_mfma_f32_16x16x32_bf16(ha[ks], wf[gate][ks + 8], acc[gate], 0, 0, 0);
    }

    // gate order (cudnn-compatible): i, g, f, o — publish h^{t+1} (tag t+2)
    unsigned int* hw = hb + (size_t)((t + 1) & 1) * (BATCH * DIMS);
    const unsigned int ptag = (unsigned int)(t + 2) << 16;
    #pragma unroll
    for (int j = 0; j < 4; ++j) {
      const float gi = acc[0][j], gg = acc[1][j], gf = acc[2][j], go = acc[3][j];
      const float cn = sigm(gf) * c[j] + sigm(gi) * tanh_(gg);
      const float hn = tanh_(cn) * sigm(go);
      if (t < Ld[j]) { c[j] = cn; h[j] = hn; }   // freeze at t >= length
      unsigned int val = ptag | (unsigned int)f2bf(h[j]);
      const unsigned int* ap = hw + (b0 + j) * DIMS + dim;
      asm volatile("global_store_dword %0, %1, off sc1"
                   :: "v"(ap), "v"(val) : "memory");
    }
  }

  // final frozen h in f32
  #pragma unroll
  for (int j = 0; j < 4; ++j)
    hfinal[((size_t)d * BATCH + b0 + j) * DIMS + dim] = h[j];
}

// ---- out[64,256] = concat(h_f, h_b) @ W_fc[512,256], f32 ----
__global__ void final_gemm(const float* __restrict__ hfinal, const float* __restrict__ Wfc,
                           float* __restrict__ out) {
  __shared__ float hrow[512];
  const int b = blockIdx.x, col = threadIdx.x;
  hrow[col]       = hfinal[(size_t)b * DIMS + col];
  hrow[256 + col] = hfinal[(size_t)(BATCH + b) * DIMS + col];
  __syncthreads();
  float acc = 0.f;
  #pragma unroll 8
  for (int k = 0; k < 512; ++k) acc = fmaf(hrow[k], Wfc[(size_t)k * DIMS + col], acc);
  out[(size_t)b * DIMS + col] = acc;
}

extern "C" void kernel_launch(void* const* d_in, const int* in_sizes, int n_in,
                              void* d_out, int out_size, void* d_ws, size_t ws_size,
                              hipStream_t stream) {
  const float* x        = (const float*)d_in[0];
  const int*   length   = (const int*)d_in[1];
  const float* W_f      = (const float*)d_in[2];
  const float* b_f      = (const float*)d_in[3];
  const float* W_b      = (const float*)d_in[4];
  const float* b_b      = (const float*)d_in[5];
  const float* c_init_f = (const float*)d_in[6];
  const float* h_init_f = (const float*)d_in[7];
  const float* c_init_b = (const float*)d_in[8];
  const float* h_init_b = (const float*)d_in[9];
  const float* W_fc     = (const float*)d_in[10];
  float* out = (float*)d_out;

  char* ws = (char*)d_ws;
  unsigned short* xbf = (unsigned short*)(ws);                       // 16,777,216 B
  unsigned short* WT  = (unsigned short*)(ws + 16777216);            //  2,097,152 B
  unsigned int*   hbf = (unsigned int*)(ws + 16777216 + 2097152);    //    524,288 B
  float* hfinal       = (float*)(ws + 16777216 + 2097152 + 524288);  //    131,072 B

  // zero tags each call (deterministic across graph replays)
  hipMemsetAsync(hbf, 0, NDIR * 2 * BATCH * DIMS * sizeof(unsigned int), stream);
  prep_x<<<8192, 256, 0, stream>>>(x, xbf);
  prep_w<<<2048, 512, 0, stream>>>(W_f, W_b, WT);
  lstm_rec<<<NBLK * NDIR, 256, 0, stream>>>(xbf, WT, b_f, b_b,
                                            c_init_f, h_init_f, c_init_b, h_init_b,
                                            length, hbf, hfinal);
  final_gemm<<<BATCH, 256, 0, stream>>>(hfinal, W_fc, out);
}

// Round 8
// 2418.600 us; speedup vs baseline: 754.6289x; 1.1009x over previous
//
#include <hip/hip_runtime.h>

#define T_STEPS 512
#define BATCH   64
#define DIMS    256
#define NBLK    16   // blocks per direction
#define NDIR    2

typedef short bf16x8 __attribute__((ext_vector_type(8)));
typedef float f32x4  __attribute__((ext_vector_type(4)));
typedef unsigned int u32x4 __attribute__((ext_vector_type(4)));

__device__ __forceinline__ unsigned short f2bf(float f) {
  union { float f; unsigned int u; } v; v.f = f;
  unsigned int b = v.u;
  return (unsigned short)((b + 0x7FFFu + ((b >> 16) & 1u)) >> 16);
}

__device__ __forceinline__ float sigm(float x) {
  return __builtin_amdgcn_rcpf(1.0f + __builtin_amdgcn_exp2f(-1.44269504f * x));
}
__device__ __forceinline__ float tanh_(float x) {
  return 1.0f - 2.0f * __builtin_amdgcn_rcpf(1.0f + __builtin_amdgcn_exp2f(2.88539008f * x));
}

__device__ __forceinline__ f32x4 bcast4(float s) {
  f32x4 v; v[0] = s; v[1] = s; v[2] = s; v[3] = s; return v;
}

// ---- prep: x (f32) -> bf16, [64][512][256] layout unchanged ----
__global__ void prep_x(const float* __restrict__ x, unsigned short* __restrict__ xbf) {
  size_t i = ((size_t)blockIdx.x * 256 + threadIdx.x) * 4;
  const float4 v = *reinterpret_cast<const float4*>(x + i);
  uint2 o;
  o.x = (unsigned)f2bf(v.x) | ((unsigned)f2bf(v.y) << 16);
  o.y = (unsigned)f2bf(v.z) | ((unsigned)f2bf(v.w) << 16);
  *reinterpret_cast<uint2*>(xbf + i) = o;
}

// ---- prep: W [512][1024] f32 -> WT [2][1024 cols][512 k] bf16 (transposed) ----
__global__ void prep_w(const float* __restrict__ Wf, const float* __restrict__ Wb,
                       unsigned short* __restrict__ WT) {
  int d = blockIdx.x >> 10, col = blockIdx.x & 1023;
  const float* W = d ? Wb : Wf;
  int k = threadIdx.x;
  WT[((size_t)(d * 1024 + col)) * 512 + k] = f2bf(W[(size_t)k * 1024 + col]);
}

// ---- persistent recurrence: 32 blocks (16/dir), W register-resident ----
// R4 structure exactly, with TWO-PHASE detection:
//   producers: 4 tagged h-stores (sc0 sc1) -> s_waitcnt vmcnt(0) -> counter
//              store cnt[dir][wv][g] = t+2 (64B line per (dir,wave) group).
//   consumers: spin on the 64B counter line (broadcast load, ~1 req/wave/rnd)
//              then load tagged h ONCE; tag-verify loop kept as safety net
//              (degenerates to R4's poll if store->store visibility reorders).
// All spins bounded so a wedge fails visibly (absmax) instead of hanging.
__global__ __launch_bounds__(256, 1) void lstm_rec(
    const unsigned short* __restrict__ xbf,   // [64][512][256] bf16
    const unsigned short* __restrict__ WT,    // [2][1024][512] bf16
    const float* __restrict__ bias_f, const float* __restrict__ bias_b,
    const float* __restrict__ ci_f, const float* __restrict__ hi_f,
    const float* __restrict__ ci_b, const float* __restrict__ hi_b,
    const int* __restrict__ length,
    unsigned int* hbuf,     // [2 dir][2 slot][64][256] u32 (tag<<16 | bf16 h)
    float* hfinal,          // [2 dir][64][256] f32
    int* cnt)               // [2 dir][4 wave][16 blk] step counters
{
  const int blk = blockIdx.x;
  const int d = blk >> 4, g = blk & 15;
  const int lane = threadIdx.x & 63;
  const int wv = threadIdx.x >> 6;
  const int lhi = lane >> 4, llo = lane & 15;

  const float* bias = d ? bias_b : bias_f;
  const float* cini = d ? ci_b : ci_f;
  const float* hini = d ? hi_b : hi_f;
  unsigned int* hb = hbuf + (size_t)d * (2 * BATCH * DIMS);
  int* cl = cnt + (d * 4 + wv) * 16;   // this wave-group's 64B counter line

  const int dim = g * 16 + llo;   // owned h-dim (MFMA N-col within tile = llo)

  // B-fragments of W: wf[gate][kstep], ks 0..7 = x rows, 8..15 = h rows.
  // Pinned via volatile asm so the loads cannot be rematerialized in-loop.
  bf16x8 wf[4][16];
  #pragma unroll
  for (int gate = 0; gate < 4; ++gate) {
    #pragma unroll
    for (int ks = 0; ks < 16; ++ks) {
      const unsigned short* p =
          WT + ((size_t)(d * 1024 + gate * 256 + dim)) * 512 + ks * 32 + lhi * 8;
      wf[gate][ks] = *reinterpret_cast<const bf16x8*>(p);
      asm volatile("" : "+v"(wf[gate][ks]));
    }
  }
  float bs[4];
  #pragma unroll
  for (int gate = 0; gate < 4; ++gate) bs[gate] = bias[gate * 256 + dim];

  // C/D layout: row(batch) = wv*16 + lhi*4 + j, col(dim) = llo
  const int b0 = wv * 16 + lhi * 4;
  float c[4], h[4];
  int Ld[4];
  #pragma unroll
  for (int j = 0; j < 4; ++j) {
    c[j] = cini[dim]; h[j] = hini[dim]; Ld[j] = length[b0 + j];
  }

  // A layout: row(batch) = wv*16 + llo, k = kstep*32 + lhi*8 + e
  const int bx = wv * 16 + llo;
  const int Lx = length[bx];

  // publish h^0 (tag=1) into slot 0, drain, then counter = 1
  #pragma unroll
  for (int j = 0; j < 4; ++j) {
    unsigned int val = (1u << 16) | (unsigned int)f2bf(h[j]);
    const unsigned int* ap = hb + (b0 + j) * DIMS + dim;
    asm volatile("global_store_dword %0, %1, off sc0 sc1"
                 :: "v"(ap), "v"(val) : "memory");
  }
  asm volatile("s_waitcnt vmcnt(0)" ::: "memory");
  if (lane == 0) {
    int one = 1;
    const int* ap = cl + g;
    asm volatile("global_store_dword %0, %1, off sc0 sc1"
                 :: "v"(ap), "v"(one) : "memory");
  }

  // preload x A-fragments for t=0 (normal cached loads)
  bf16x8 xa[8];
  {
    const int tx0 = (d == 0) ? 0 : (Lx - 1);
    const unsigned short* xp = xbf + ((size_t)bx * T_STEPS + tx0) * DIMS + lhi * 8;
    #pragma unroll
    for (int ks = 0; ks < 8; ++ks) xa[ks] = *reinterpret_cast<const bf16x8*>(xp + ks * 32);
  }

  #pragma unroll 1
  for (int t = 0; t < T_STEPS; ++t) {
    f32x4 acc[4];
    #pragma unroll
    for (int gate = 0; gate < 4; ++gate) acc[gate] = bcast4(bs[gate]);

    // x-part (independent of h^t): runs while producers finish step t-1
    #pragma unroll
    for (int ks = 0; ks < 8; ++ks) {
      #pragma unroll
      for (int gate = 0; gate < 4; ++gate)
        acc[gate] = __builtin_amdgcn_mfma_f32_16x16x32_bf16(xa[ks], wf[gate][ks], acc[gate], 0, 0, 0);
    }

    // phase 1: spin on the counter line (64B, broadcast) until all 16 >= t+1
    {
      const int* cp = cl + (lane & 15);
      bool ok;
      unsigned int spins = 0;
      do {
        int v;
        asm volatile("global_load_dword %0, %1, off sc0 sc1"
                     : "=v"(v) : "v"(cp) : "memory");
        asm volatile("s_waitcnt vmcnt(0)" ::: "memory");
        __builtin_amdgcn_sched_barrier(0);
        ok = (v >= t + 1);
        if (++spins > (1u << 22)) ok = true;   // escape -> visible absmax fail
      } while (!__all(ok));
    }

    // phase 2: load own k-slice of h^t once; tag-verify (safety net loop)
    const unsigned int* hr = hb + (size_t)(t & 1) * (BATCH * DIMS) + bx * DIMS + lhi * 8;
    u32x4 w[16];
    {
      const unsigned int tagsh = (unsigned int)(t + 1) << 16;
      bool ready;
      unsigned int spins = 0;
      do {
        #pragma unroll
        for (int ks = 0; ks < 8; ++ks) {
          const unsigned int* p = hr + ks * 32;
          asm volatile("global_load_dwordx4 %0, %1, off sc0 sc1"
                       : "=v"(w[2 * ks]) : "v"(p) : "memory");
          asm volatile("global_load_dwordx4 %0, %1, off sc0 sc1"
                       : "=v"(w[2 * ks + 1]) : "v"(p + 4) : "memory");
        }
        asm volatile("s_waitcnt vmcnt(0)" ::: "memory");
        __builtin_amdgcn_sched_barrier(0);
        unsigned int bad = 0;
        #pragma unroll
        for (int i = 0; i < 16; ++i)
          #pragma unroll
          for (int q = 0; q < 4; ++q)
            bad |= (w[i][q] ^ tagsh);
        ready = ((bad >> 16) == 0);
        if (++spins > (1u << 16)) ready = true;   // escape -> visible fail
      } while (!__all(ready));
    }
    __builtin_amdgcn_sched_barrier(0);

    // repack low halves -> bf16x8 A-fragments
    bf16x8 ha[8];
    #pragma unroll
    for (int ks = 0; ks < 8; ++ks) {
      union { bf16x8 v; unsigned int dd[4]; } u;
      u.dd[0] = (w[2 * ks][0]     & 0xFFFFu) | (w[2 * ks][1]     << 16);
      u.dd[1] = (w[2 * ks][2]     & 0xFFFFu) | (w[2 * ks][3]     << 16);
      u.dd[2] = (w[2 * ks + 1][0] & 0xFFFFu) | (w[2 * ks + 1][1] << 16);
      u.dd[3] = (w[2 * ks + 1][2] & 0xFFFFu) | (w[2 * ks + 1][3] << 16);
      ha[ks] = u.v;
    }

    // prefetch x A-fragments for t+1 (cached; drained by the publish vmcnt)
    if (t + 1 < T_STEPS) {
      const int tn = t + 1;
      const int tx = (d == 0) ? tn : ((tn < Lx) ? (Lx - 1 - tn) : tn);
      const unsigned short* xp = xbf + ((size_t)bx * T_STEPS + tx) * DIMS + lhi * 8;
      #pragma unroll
      for (int ks = 0; ks < 8; ++ks) xa[ks] = *reinterpret_cast<const bf16x8*>(xp + ks * 32);
    }

    #pragma unroll
    for (int ks = 0; ks < 8; ++ks) {
      #pragma unroll
      for (int gate = 0; gate < 4; ++gate)
        acc[gate] = __builtin_amdgcn_mfma_f32_16x16x32_bf16(ha[ks], wf[gate][ks + 8], acc[gate], 0, 0, 0);
    }

    // gate order (cudnn-compatible): i, g, f, o — publish h^{t+1} (tag t+2)
    unsigned int* hw = hb + (size_t)((t + 1) & 1) * (BATCH * DIMS);
    const unsigned int ptag = (unsigned int)(t + 2) << 16;
    #pragma unroll
    for (int j = 0; j < 4; ++j) {
      const float gi = acc[0][j], gg = acc[1][j], gf = acc[2][j], go = acc[3][j];
      const float cn = sigm(gf) * c[j] + sigm(gi) * tanh_(gg);
      const float hn = tanh_(cn) * sigm(go);
      if (t < Ld[j]) { c[j] = cn; h[j] = hn; }   // freeze at t >= length
      unsigned int val = ptag | (unsigned int)f2bf(h[j]);
      const unsigned int* ap = hw + (b0 + j) * DIMS + dim;
      asm volatile("global_store_dword %0, %1, off sc0 sc1"
                   :: "v"(ap), "v"(val) : "memory");
    }

    // drain h stores, then bump this block's counter to t+2
    asm volatile("s_waitcnt vmcnt(0)" ::: "memory");
    if (lane == 0) {
      int nv = t + 2;
      const int* ap = cl + g;
      asm volatile("global_store_dword %0, %1, off sc0 sc1"
                   :: "v"(ap), "v"(nv) : "memory");
    }
  }

  // final frozen h in f32
  #pragma unroll
  for (int j = 0; j < 4; ++j)
    hfinal[((size_t)d * BATCH + b0 + j) * DIMS + dim] = h[j];
}

// ---- out[64,256] = concat(h_f, h_b) @ W_fc[512,256], f32 ----
__global__ void final_gemm(const float* __restrict__ hfinal, const float* __restrict__ Wfc,
                           float* __restrict__ out) {
  __shared__ float hrow[512];
  const int b = blockIdx.x, col = threadIdx.x;
  hrow[col]       = hfinal[(size_t)b * DIMS + col];
  hrow[256 + col] = hfinal[(size_t)(BATCH + b) * DIMS + col];
  __syncthreads();
  float acc = 0.f;
  #pragma unroll 8
  for (int k = 0; k < 512; ++k) acc = fmaf(hrow[k], Wfc[(size_t)k * DIMS + col], acc);
  out[(size_t)b * DIMS + col] = acc;
}

extern "C" void kernel_launch(void* const* d_in, const int* in_sizes, int n_in,
                              void* d_out, int out_size, void* d_ws, size_t ws_size,
                              hipStream_t stream) {
  const float* x        = (const float*)d_in[0];
  const int*   length   = (const int*)d_in[1];
  const float* W_f      = (const float*)d_in[2];
  const float* b_f      = (const float*)d_in[3];
  const float* W_b      = (const float*)d_in[4];
  const float* b_b      = (const float*)d_in[5];
  const float* c_init_f = (const float*)d_in[6];
  const float* h_init_f = (const float*)d_in[7];
  const float* c_init_b = (const float*)d_in[8];
  const float* h_init_b = (const float*)d_in[9];
  const float* W_fc     = (const float*)d_in[10];
  float* out = (float*)d_out;

  char* ws = (char*)d_ws;
  unsigned short* xbf = (unsigned short*)(ws);                       // 16,777,216 B
  unsigned short* WT  = (unsigned short*)(ws + 16777216);            //  2,097,152 B
  unsigned int*   hbf = (unsigned int*)(ws + 16777216 + 2097152);    //    524,288 B
  int*   cnt          = (int*)(ws + 16777216 + 2097152 + 524288);    //      4,096 B
  float* hfinal       = (float*)(ws + 16777216 + 2097152 + 524288 + 4096);  // 131,072 B

  // zero h tags + counters each call (contiguous; deterministic across replays)
  hipMemsetAsync(hbf, 0, 524288 + 4096, stream);
  prep_x<<<8192, 256, 0, stream>>>(x, xbf);
  prep_w<<<2048, 512, 0, stream>>>(W_f, W_b, WT);
  lstm_rec<<<NBLK * NDIR, 256, 0, stream>>>(xbf, WT, b_f, b_b,
                                            c_init_f, h_init_f, c_init_b, h_init_b,
                                            length, hbf, hfinal, cnt);
  final_gemm<<<BATCH, 256, 0, stream>>>(hfinal, W_fc, out);
}